// Round 1
// baseline (163.887 us; speedup 1.0000x reference)
//
#include <hip/hip_runtime.h>
#include <hip/hip_bf16.h>
#include <math.h>

typedef __attribute__((ext_vector_type(8))) __bf16 bf16x8;
typedef __attribute__((ext_vector_type(4))) float f32x4;
typedef __attribute__((ext_vector_type(4))) float float4_t;
typedef __attribute__((ext_vector_type(4))) unsigned int uint4_t;

#define NB 4
#define TSEQ 4096
#define CD 1024
#define HD 64

static __device__ __forceinline__ unsigned short f2bf(float f) {
    union { float f; unsigned u; } v; v.f = f;
    unsigned r = v.u + 0x7fffu + ((v.u >> 16) & 1u);
    return (unsigned short)(r >> 16);
}

// ---------------- W f32 -> bf16 (concatenated [192][1024]) ----------------
__global__ __launch_bounds__(256) void wcvt_kernel(const float* __restrict__ wq,
                                                   const float* __restrict__ wk,
                                                   const float* __restrict__ wv,
                                                   unsigned short* __restrict__ wb) {
    int i = blockIdx.x * 256 + threadIdx.x;
    if (i >= 3 * HD * CD) return;
    int which = i >> 16;  // HD*CD == 65536
    const float* src = (which == 0) ? wq : ((which == 1) ? wk : wv);
    wb[i] = f2bf(src[i & 0xFFFF]);
}

// ---------------- fused QKV projection + RoPE ----------------
// grid: 256 blocks (64 rows each), 256 threads (4 waves)
// out: q,k bf16 [B*T][64] (RoPE'd), v transposed bf16 [B][64][T]
__global__ __launch_bounds__(256) void qkv_kernel(const float* __restrict__ x,
                                                  const unsigned short* __restrict__ wb,
                                                  unsigned short* __restrict__ qo,
                                                  unsigned short* __restrict__ ko,
                                                  unsigned short* __restrict__ vt) {
    __shared__ unsigned short xs[64][72];
    __shared__ unsigned short wsm[192][72];
    const int tid = threadIdx.x;
    const int wave = tid >> 6, lane = tid & 63;
    const int lr = lane & 15;
    const int lk = (lane >> 4) << 3;
    const int rowg = (lane >> 4) << 2;
    const int row0 = blockIdx.x * 64;

    f32x4 acc[12];
#pragma unroll
    for (int i = 0; i < 12; ++i) acc[i] = (f32x4){0.f, 0.f, 0.f, 0.f};

    for (int k0 = 0; k0 < CD; k0 += 64) {
        __syncthreads();
        {   // stage x tile 64x64 f32 -> bf16
            int r = tid >> 2;
            int c0 = (tid & 3) << 4;
            const float4_t* s4 =
                reinterpret_cast<const float4_t*>(x + (size_t)(row0 + r) * CD + k0 + c0);
            alignas(16) unsigned short tmp[16];
#pragma unroll
            for (int j = 0; j < 4; ++j) {
                float4_t f = s4[j];
#pragma unroll
                for (int e = 0; e < 4; ++e) tmp[j * 4 + e] = f2bf(f[e]);
            }
            *reinterpret_cast<uint4_t*>(&xs[r][c0]) = *reinterpret_cast<const uint4_t*>(&tmp[0]);
            *reinterpret_cast<uint4_t*>(&xs[r][c0 + 8]) = *reinterpret_cast<const uint4_t*>(&tmp[8]);
        }
#pragma unroll
        for (int i = 0; i < 6; ++i) {  // stage W tile 192x64 bf16
            int c = tid + (i << 8);
            int r = c >> 3;
            int c8 = (c & 7) << 3;
            *reinterpret_cast<uint4_t*>(&wsm[r][c8]) =
                *reinterpret_cast<const uint4_t*>(wb + (size_t)r * CD + k0 + c8);
        }
        __syncthreads();
#pragma unroll
        for (int kk = 0; kk < 2; ++kk) {
            bf16x8 a = *reinterpret_cast<const bf16x8*>(&xs[wave * 16 + lr][kk * 32 + lk]);
#pragma unroll
            for (int c = 0; c < 12; ++c) {
                bf16x8 bfr = *reinterpret_cast<const bf16x8*>(&wsm[c * 16 + lr][kk * 32 + lk]);
                acc[c] = __builtin_amdgcn_mfma_f32_16x16x32_bf16(a, bfr, acc[c], 0, 0, 0);
            }
        }
    }

    // epilogue: RoPE on q (cols 0..63 = acc[0..3]) and k (acc[4..7]); v = acc[8..11]
    const int bidx = row0 >> 12;
    const int tbase = (row0 & (TSEQ - 1)) + wave * 16 + rowg;
    const float l2b = 13.287712379549449f / 32.0f;  // log2(10000)/32
    const float invf0 = exp2f(-(float)lr * l2b);
    const float invf1 = exp2f(-(float)(lr + 16) * l2b);
#pragma unroll
    for (int r = 0; r < 4; ++r) {
        float t = (float)(tbase + r);
        float s0, c0, s1, c1;
        sincosf(t * invf0, &s0, &c0);
        sincosf(t * invf1, &s1, &c1);
        float q0 = acc[0][r], q1 = acc[1][r], q2 = acc[2][r], q3 = acc[3][r];
        float k0v = acc[4][r], k1v = acc[5][r], k2v = acc[6][r], k3v = acc[7][r];
        float nq0 = q0 * c0 - q2 * s0, nq1 = q1 * c1 - q3 * s1;
        float nq2 = q2 * c0 + q0 * s0, nq3 = q3 * c1 + q1 * s1;
        float nk0 = k0v * c0 - k2v * s0, nk1 = k1v * c1 - k3v * s1;
        float nk2 = k2v * c0 + k0v * s0, nk3 = k3v * c1 + k1v * s1;
        size_t rowoff = (size_t)(row0 + wave * 16 + rowg + r) * HD;
        qo[rowoff + 0 + lr] = f2bf(nq0);
        qo[rowoff + 16 + lr] = f2bf(nq1);
        qo[rowoff + 32 + lr] = f2bf(nq2);
        qo[rowoff + 48 + lr] = f2bf(nq3);
        ko[rowoff + 0 + lr] = f2bf(nk0);
        ko[rowoff + 16 + lr] = f2bf(nk1);
        ko[rowoff + 32 + lr] = f2bf(nk2);
        ko[rowoff + 48 + lr] = f2bf(nk3);
        int tg = tbase + r;
        size_t vbase = (size_t)bidx * HD * TSEQ + tg;
        vt[vbase + (size_t)(0 + lr) * TSEQ] = f2bf(acc[8][r]);
        vt[vbase + (size_t)(16 + lr) * TSEQ] = f2bf(acc[9][r]);
        vt[vbase + (size_t)(32 + lr) * TSEQ] = f2bf(acc[10][r]);
        vt[vbase + (size_t)(48 + lr) * TSEQ] = f2bf(acc[11][r]);
    }
}

// ---------------- causal flash attention ----------------
// grid: B*64 blocks; block = 4 waves, each owns 16 q-rows (QBLK=64); KVBLK=64
__global__ __launch_bounds__(256) void attn_kernel(const unsigned short* __restrict__ q,
                                                   const unsigned short* __restrict__ k,
                                                   const unsigned short* __restrict__ vt,
                                                   float* __restrict__ out) {
    __shared__ unsigned short ks[64][72];
    __shared__ unsigned short vs[64][72];
    __shared__ unsigned short ps[4][16][72];
    const int tid = threadIdx.x;
    const int wave = tid >> 6, lane = tid & 63;
    const int lr = lane & 15;
    const int lk = (lane >> 4) << 3;
    const int rowg = (lane >> 4) << 2;
    const int b = blockIdx.x >> 6;
    const int qt = blockIdx.x & 63;
    const int qrow0 = qt * 64 + wave * 16;  // within batch

    // Q fragments (A operand): lane -> Q[qrow0+lr][lk..lk+7 (+32)]
    const unsigned short* qbase = q + ((size_t)(b * TSEQ + qrow0 + lr)) * HD;
    bf16x8 qf0 = *reinterpret_cast<const bf16x8*>(qbase + lk);
    bf16x8 qf1 = *reinterpret_cast<const bf16x8*>(qbase + 32 + lk);

    f32x4 oacc[4];
#pragma unroll
    for (int i = 0; i < 4; ++i) oacc[i] = (f32x4){0.f, 0.f, 0.f, 0.f};
    float m[4] = {-INFINITY, -INFINITY, -INFINITY, -INFINITY};
    float lsum[4] = {0.f, 0.f, 0.f, 0.f};
    const float scale = 0.03125f;  // 1024^-0.5

    for (int kt = 0; kt <= qt; ++kt) {
        const int s0 = kt * 64;
        __syncthreads();
#pragma unroll
        for (int i = 0; i < 2; ++i) {  // stage K [s][h] and V^T [h][s] tiles
            int c = tid + (i << 8);
            int r = c >> 3;
            int c8 = (c & 7) << 3;
            *reinterpret_cast<uint4_t*>(&ks[r][c8]) =
                *reinterpret_cast<const uint4_t*>(k + (size_t)(b * TSEQ + s0 + r) * HD + c8);
            *reinterpret_cast<uint4_t*>(&vs[r][c8]) =
                *reinterpret_cast<const uint4_t*>(vt + ((size_t)b * HD + r) * TSEQ + s0 + c8);
        }
        __syncthreads();

        // S = Q K^T  (4 s-fragments of 16)
        float sv[4][4];
        const bool diag = (kt == qt);
#pragma unroll
        for (int sc = 0; sc < 4; ++sc) {
            bf16x8 b0 = *reinterpret_cast<const bf16x8*>(&ks[sc * 16 + lr][lk]);
            bf16x8 b1 = *reinterpret_cast<const bf16x8*>(&ks[sc * 16 + lr][32 + lk]);
            f32x4 z = (f32x4){0.f, 0.f, 0.f, 0.f};
            z = __builtin_amdgcn_mfma_f32_16x16x32_bf16(qf0, b0, z, 0, 0, 0);
            z = __builtin_amdgcn_mfma_f32_16x16x32_bf16(qf1, b1, z, 0, 0, 0);
#pragma unroll
            for (int r = 0; r < 4; ++r) {
                float v = z[r] * scale;
                if (diag && (s0 + sc * 16 + lr) > (qrow0 + rowg + r)) v = -INFINITY;
                sv[sc][r] = v;
            }
        }

        // online softmax per q-row (row r lives in 16-lane group, cols = lr)
#pragma unroll
        for (int r = 0; r < 4; ++r) {
            float mx = fmaxf(fmaxf(sv[0][r], sv[1][r]), fmaxf(sv[2][r], sv[3][r]));
#pragma unroll
            for (int off = 1; off < 16; off <<= 1) mx = fmaxf(mx, __shfl_xor(mx, off, 64));
            float mnew = fmaxf(m[r], mx);
            float corr = __expf(m[r] - mnew);
            m[r] = mnew;
            float psum = 0.f;
#pragma unroll
            for (int sc = 0; sc < 4; ++sc) {
                float p = __expf(sv[sc][r] - mnew);
                psum += p;
                ps[wave][rowg + r][sc * 16 + lr] = f2bf(p);
            }
#pragma unroll
            for (int off = 1; off < 16; off <<= 1) psum += __shfl_xor(psum, off, 64);
            lsum[r] = lsum[r] * corr + psum;
#pragma unroll
            for (int hc = 0; hc < 4; ++hc) oacc[hc][r] *= corr;
        }

        // P V  (re-read P from per-wave LDS in A-operand layout)
        bf16x8 pf0 = *reinterpret_cast<const bf16x8*>(&ps[wave][lr][lk]);
        bf16x8 pf1 = *reinterpret_cast<const bf16x8*>(&ps[wave][lr][32 + lk]);
#pragma unroll
        for (int hc = 0; hc < 4; ++hc) {
            bf16x8 v0 = *reinterpret_cast<const bf16x8*>(&vs[hc * 16 + lr][lk]);
            bf16x8 v1 = *reinterpret_cast<const bf16x8*>(&vs[hc * 16 + lr][32 + lk]);
            oacc[hc] = __builtin_amdgcn_mfma_f32_16x16x32_bf16(pf0, v0, oacc[hc], 0, 0, 0);
            oacc[hc] = __builtin_amdgcn_mfma_f32_16x16x32_bf16(pf1, v1, oacc[hc], 0, 0, 0);
        }
    }

    // epilogue
#pragma unroll
    for (int hc = 0; hc < 4; ++hc) {
#pragma unroll
        for (int r = 0; r < 4; ++r) {
            out[(size_t)(b * TSEQ + qrow0 + rowg + r) * HD + hc * 16 + lr] =
                oacc[hc][r] / lsum[r];
        }
    }
}

extern "C" void kernel_launch(void* const* d_in, const int* in_sizes, int n_in,
                              void* d_out, int out_size, void* d_ws, size_t ws_size,
                              hipStream_t stream) {
    const float* x = (const float*)d_in[0];
    const float* wq = (const float*)d_in[1];
    const float* wk = (const float*)d_in[2];
    const float* wv = (const float*)d_in[3];
    float* out = (float*)d_out;

    unsigned short* wb = (unsigned short*)d_ws;          // 196608
    unsigned short* qb = wb + 3 * HD * CD;               // 1048576
    unsigned short* kb = qb + (size_t)NB * TSEQ * HD;    // 1048576
    unsigned short* vtb = kb + (size_t)NB * TSEQ * HD;   // 1048576

    wcvt_kernel<<<768, 256, 0, stream>>>(wq, wk, wv, wb);
    qkv_kernel<<<256, 256, 0, stream>>>(x, wb, qb, kb, vtb);
    attn_kernel<<<NB * 64, 256, 0, stream>>>(qb, kb, vtb, out);
}

// Round 2
// 136.752 us; speedup vs baseline: 1.1984x; 1.1984x over previous
//
#include <hip/hip_runtime.h>
#include <hip/hip_bf16.h>
#include <math.h>

typedef __attribute__((ext_vector_type(8))) __bf16 bf16x8;
typedef __attribute__((ext_vector_type(4))) float f32x4;
typedef __attribute__((ext_vector_type(4))) float float4_t;
typedef __attribute__((ext_vector_type(4))) unsigned int uint4_t;

#define NB 4
#define TSEQ 4096
#define CD 1024
#define HD 64
#define NCH 8      // max KV chunks per q-tile
#define CHT 8      // KV tiles (of 64) per chunk

static __device__ __forceinline__ unsigned short f2bf(float f) {
    union { float f; unsigned u; } v; v.f = f;
    unsigned r = v.u + 0x7fffu + ((v.u >> 16) & 1u);
    return (unsigned short)(r >> 16);
}

// ---------------- W f32 -> bf16, permuted rows ----------------
// dest row blocks of 16: [q0,q32,q16,q48, k0,k32,k16,k48, v0,v16,v32,v48]
// so every RoPE (h,h+32) pair is an adjacent 16-row block pair.
__global__ __launch_bounds__(256) void wcvt_kernel(const float* __restrict__ wq,
                                                   const float* __restrict__ wk,
                                                   const float* __restrict__ wv,
                                                   unsigned short* __restrict__ wb) {
    int i = blockIdx.x * 256 + threadIdx.x;   // over 192*1024
    int j = i >> 10;                          // dest row
    int col = i & 1023;
    int jb = j >> 4, off = j & 15;
    int sub = ((jb & 1) << 5) | ((jb & 2) << 3);  // 0,32,16,48
    int srcrow = (jb < 8) ? (sub + off) : ((jb - 8) * 16 + off);
    const float* src = (jb < 4) ? wq : ((jb < 8) ? wk : wv);
    wb[i] = f2bf(src[srcrow * 1024 + col]);
}

// ---------------- fused QKV projection + RoPE (no LDS) ----------------
// grid: 512 blocks x 32 rows; 4 waves: (wr=row half, wc=col half of 96)
__global__ __launch_bounds__(256) void qkv_kernel(const float* __restrict__ x,
                                                  const unsigned short* __restrict__ wb,
                                                  unsigned short* __restrict__ qo,
                                                  unsigned short* __restrict__ ko,
                                                  unsigned short* __restrict__ vt) {
    const int tid = threadIdx.x;
    const int wave = tid >> 6, lane = tid & 63;
    const int lr = lane & 15;
    const int lk = (lane >> 4) << 3;
    const int rowg = (lane >> 4) << 2;
    const int wr = wave & 1, wc = wave >> 1;
    const int row0 = blockIdx.x * 32 + wr * 16;
    const int colb = wc * 96;

    f32x4 acc[6];
#pragma unroll
    for (int i = 0; i < 6; ++i) acc[i] = (f32x4){0.f, 0.f, 0.f, 0.f};

    const float* xrow = x + (size_t)(row0 + lr) * CD;

#pragma unroll 4
    for (int k0 = 0; k0 < CD; k0 += 64) {
        bf16x8 a0, a1;
        {
            const float4_t* p0 = reinterpret_cast<const float4_t*>(xrow + k0 + lk);
            float4_t f0 = p0[0], f1 = p0[1];
            const float4_t* p1 = reinterpret_cast<const float4_t*>(xrow + k0 + 32 + lk);
            float4_t g0 = p1[0], g1 = p1[1];
#pragma unroll
            for (int e = 0; e < 4; ++e) {
                a0[e] = (__bf16)f0[e];
                a0[4 + e] = (__bf16)f1[e];
                a1[e] = (__bf16)g0[e];
                a1[4 + e] = (__bf16)g1[e];
            }
        }
#pragma unroll
        for (int c = 0; c < 6; ++c) {
            const unsigned short* wp = wb + (size_t)(colb + c * 16 + lr) * CD + k0;
            bf16x8 b0 = *reinterpret_cast<const bf16x8*>(wp + lk);
            bf16x8 b1 = *reinterpret_cast<const bf16x8*>(wp + 32 + lk);
            acc[c] = __builtin_amdgcn_mfma_f32_16x16x32_bf16(a0, b0, acc[c], 0, 0, 0);
            acc[c] = __builtin_amdgcn_mfma_f32_16x16x32_bf16(a1, b1, acc[c], 0, 0, 0);
        }
    }

    // epilogue: RoPE + store.  acc[c] -> feature col block bp = wc*6+c
    const float l2b = 0.4152410118609215f;  // log2(10000)/32
    const float invf0 = exp2f(-(float)lr * l2b);
    const float invf1 = exp2f(-(float)(lr + 16) * l2b);
    const int growb = row0 + rowg;
    const int bidx = growb >> 12;
    const int tb = growb & (TSEQ - 1);
#pragma unroll
    for (int r = 0; r < 4; ++r) {
        float t = (float)(tb + r);
        float s0, c0, s1, c1;
        sincosf(t * invf0, &s0, &c0);
        sincosf(t * invf1, &s1, &c1);
        size_t ro = (size_t)(growb + r) * HD;
        if (wc == 0) {
            // (0,1)=q[0|32] hb0; (2,3)=q[16|48] hb16; (4,5)=k[0|32] hb0
            float lo, hi;
            lo = acc[0][r]; hi = acc[1][r];
            qo[ro + 0 + lr]  = f2bf(lo * c0 - hi * s0);
            qo[ro + 32 + lr] = f2bf(hi * c0 + lo * s0);
            lo = acc[2][r]; hi = acc[3][r];
            qo[ro + 16 + lr] = f2bf(lo * c1 - hi * s1);
            qo[ro + 48 + lr] = f2bf(hi * c1 + lo * s1);
            lo = acc[4][r]; hi = acc[5][r];
            ko[ro + 0 + lr]  = f2bf(lo * c0 - hi * s0);
            ko[ro + 32 + lr] = f2bf(hi * c0 + lo * s0);
        } else {
            // (0,1)=k[16|48] hb16; (2..5)=v[0,16,32,48]
            float lo = acc[0][r], hi = acc[1][r];
            ko[ro + 16 + lr] = f2bf(lo * c1 - hi * s1);
            ko[ro + 48 + lr] = f2bf(hi * c1 + lo * s1);
            size_t vbase = (size_t)bidx * HD * TSEQ + (size_t)(tb + r);
            vt[vbase + (size_t)(0 + lr) * TSEQ]  = f2bf(acc[2][r]);
            vt[vbase + (size_t)(16 + lr) * TSEQ] = f2bf(acc[3][r]);
            vt[vbase + (size_t)(32 + lr) * TSEQ] = f2bf(acc[4][r]);
            vt[vbase + (size_t)(48 + lr) * TSEQ] = f2bf(acc[5][r]);
        }
    }
}

// ---------------- causal flash attention, KV-split partials ----------------
// grid: (chunk=8, qt=64, b=B); block = 4 waves x 16 q-rows; KVBLK=64
__global__ __launch_bounds__(256) void attn_partial(const unsigned short* __restrict__ q,
                                                    const unsigned short* __restrict__ k,
                                                    const unsigned short* __restrict__ vt,
                                                    float* __restrict__ po,
                                                    float* __restrict__ pm,
                                                    float* __restrict__ pl) {
    const int chunk = blockIdx.x, qt = blockIdx.y, b = blockIdx.z;
    const int kt0 = chunk * CHT;
    if (kt0 > qt) return;
    const int ktend = min(qt, kt0 + CHT - 1);

    __shared__ unsigned short ks[64][72];
    __shared__ unsigned short vs[64][72];
    __shared__ unsigned short ps[4][16][72];
    const int tid = threadIdx.x;
    const int wave = tid >> 6, lane = tid & 63;
    const int lr = lane & 15;
    const int lk = (lane >> 4) << 3;
    const int rowg = (lane >> 4) << 2;
    const int qrow0 = qt * 64 + wave * 16;  // within batch

    const unsigned short* qbase = q + ((size_t)(b * TSEQ + qrow0 + lr)) * HD;
    bf16x8 qf0 = *reinterpret_cast<const bf16x8*>(qbase + lk);
    bf16x8 qf1 = *reinterpret_cast<const bf16x8*>(qbase + 32 + lk);

    f32x4 oacc[4];
#pragma unroll
    for (int i = 0; i < 4; ++i) oacc[i] = (f32x4){0.f, 0.f, 0.f, 0.f};
    float m[4] = {-INFINITY, -INFINITY, -INFINITY, -INFINITY};
    float lsum[4] = {0.f, 0.f, 0.f, 0.f};
    const float scale = 0.03125f;  // 1024^-0.5

    for (int kt = kt0; kt <= ktend; ++kt) {
        const int s0 = kt * 64;
        __syncthreads();
#pragma unroll
        for (int i = 0; i < 2; ++i) {
            int c = tid + (i << 8);
            int r = c >> 3;
            int c8 = (c & 7) << 3;
            *reinterpret_cast<uint4_t*>(&ks[r][c8]) =
                *reinterpret_cast<const uint4_t*>(k + (size_t)(b * TSEQ + s0 + r) * HD + c8);
            *reinterpret_cast<uint4_t*>(&vs[r][c8]) =
                *reinterpret_cast<const uint4_t*>(vt + ((size_t)b * HD + r) * TSEQ + s0 + c8);
        }
        __syncthreads();

        float sv[4][4];
        const bool diag = (kt == qt);
#pragma unroll
        for (int sc = 0; sc < 4; ++sc) {
            bf16x8 b0 = *reinterpret_cast<const bf16x8*>(&ks[sc * 16 + lr][lk]);
            bf16x8 b1 = *reinterpret_cast<const bf16x8*>(&ks[sc * 16 + lr][32 + lk]);
            f32x4 z = (f32x4){0.f, 0.f, 0.f, 0.f};
            z = __builtin_amdgcn_mfma_f32_16x16x32_bf16(qf0, b0, z, 0, 0, 0);
            z = __builtin_amdgcn_mfma_f32_16x16x32_bf16(qf1, b1, z, 0, 0, 0);
#pragma unroll
            for (int r = 0; r < 4; ++r) {
                float v = z[r] * scale;
                if (diag && (s0 + sc * 16 + lr) > (qrow0 + rowg + r)) v = -INFINITY;
                sv[sc][r] = v;
            }
        }

#pragma unroll
        for (int r = 0; r < 4; ++r) {
            float mx = fmaxf(fmaxf(sv[0][r], sv[1][r]), fmaxf(sv[2][r], sv[3][r]));
#pragma unroll
            for (int off = 1; off < 16; off <<= 1) mx = fmaxf(mx, __shfl_xor(mx, off, 64));
            float mnew = fmaxf(m[r], mx);
            float corr = __expf(m[r] - mnew);
            m[r] = mnew;
            float psum = 0.f;
#pragma unroll
            for (int sc = 0; sc < 4; ++sc) {
                float p = __expf(sv[sc][r] - mnew);
                psum += p;
                ps[wave][rowg + r][sc * 16 + lr] = f2bf(p);
            }
#pragma unroll
            for (int off = 1; off < 16; off <<= 1) psum += __shfl_xor(psum, off, 64);
            lsum[r] = lsum[r] * corr + psum;
#pragma unroll
            for (int hc = 0; hc < 4; ++hc) oacc[hc][r] *= corr;
        }

        bf16x8 pf0 = *reinterpret_cast<const bf16x8*>(&ps[wave][lr][lk]);
        bf16x8 pf1 = *reinterpret_cast<const bf16x8*>(&ps[wave][lr][32 + lk]);
#pragma unroll
        for (int hc = 0; hc < 4; ++hc) {
            bf16x8 v0 = *reinterpret_cast<const bf16x8*>(&vs[hc * 16 + lr][lk]);
            bf16x8 v1 = *reinterpret_cast<const bf16x8*>(&vs[hc * 16 + lr][32 + lk]);
            oacc[hc] = __builtin_amdgcn_mfma_f32_16x16x32_bf16(pf0, v0, oacc[hc], 0, 0, 0);
            oacc[hc] = __builtin_amdgcn_mfma_f32_16x16x32_bf16(pf1, v1, oacc[hc], 0, 0, 0);
        }
    }

    // write unnormalized partial + (m, l)
    const int slot = (((b << 6) + qt) << 3) + chunk;
    float* pob = po + (size_t)slot * 4096;
#pragma unroll
    for (int hc = 0; hc < 4; ++hc) {
#pragma unroll
        for (int r = 0; r < 4; ++r) {
            pob[(wave * 16 + rowg + r) * 64 + hc * 16 + lr] = oacc[hc][r];
        }
    }
    if (lr == 0) {
#pragma unroll
        for (int r = 0; r < 4; ++r) {
            pm[slot * 64 + wave * 16 + rowg + r] = m[r];
            pl[slot * 64 + wave * 16 + rowg + r] = lsum[r];
        }
    }
}

// ---------------- combine partials ----------------
__global__ __launch_bounds__(256) void attn_combine(const float* __restrict__ po,
                                                    const float* __restrict__ pm,
                                                    const float* __restrict__ pl,
                                                    float* __restrict__ out) {
    const int bq = blockIdx.x;       // b*64 + qt
    const int qt = bq & 63;
    const int nch = (qt >> 3) + 1;
    const int row = threadIdx.x >> 2;
    const int cg = (threadIdx.x & 3) << 4;
    const int sbase = bq << 3;

    float M = -INFINITY;
    for (int c = 0; c < nch; ++c) M = fmaxf(M, pm[(sbase + c) * 64 + row]);
    float L = 0.f;
    float acc[16];
#pragma unroll
    for (int j = 0; j < 16; ++j) acc[j] = 0.f;
    for (int c = 0; c < nch; ++c) {
        int s = sbase + c;
        float w = __expf(pm[s * 64 + row] - M);
        L += w * pl[s * 64 + row];
        const float4_t* p =
            reinterpret_cast<const float4_t*>(po + (size_t)s * 4096 + row * 64 + cg);
#pragma unroll
        for (int v4 = 0; v4 < 4; ++v4) {
            float4_t f = p[v4];
#pragma unroll
            for (int e = 0; e < 4; ++e) acc[v4 * 4 + e] += w * f[e];
        }
    }
    float inv = 1.f / L;
    size_t o = (size_t)bq * 4096 + row * 64 + cg;
#pragma unroll
    for (int j = 0; j < 16; ++j) out[o + j] = acc[j] * inv;
}

extern "C" void kernel_launch(void* const* d_in, const int* in_sizes, int n_in,
                              void* d_out, int out_size, void* d_ws, size_t ws_size,
                              hipStream_t stream) {
    const float* x = (const float*)d_in[0];
    const float* wq = (const float*)d_in[1];
    const float* wk = (const float*)d_in[2];
    const float* wv = (const float*)d_in[3];
    float* out = (float*)d_out;

    unsigned short* wb = (unsigned short*)d_ws;            // 196608 elems
    unsigned short* qb = wb + 3 * HD * CD;
    unsigned short* kb = qb + (size_t)NB * TSEQ * HD;
    unsigned short* vtb = kb + (size_t)NB * TSEQ * HD;
    float* po = (float*)(vtb + (size_t)NB * TSEQ * HD);    // 2048 slots * 4096 f32
    float* pm = po + (size_t)2048 * 4096;
    float* pl = pm + (size_t)2048 * 64;

    wcvt_kernel<<<768, 256, 0, stream>>>(wq, wk, wv, wb);
    qkv_kernel<<<512, 256, 0, stream>>>(x, wb, qb, kb, vtb);
    attn_partial<<<dim3(NCH, 64, NB), 256, 0, stream>>>(qb, kb, vtb, po, pm, pl);
    attn_combine<<<NB * 64, 256, 0, stream>>>(po, pm, pl, out);
}

// Round 3
// 97.043 us; speedup vs baseline: 1.6888x; 1.4092x over previous
//
#include <hip/hip_runtime.h>
#include <hip/hip_bf16.h>
#include <math.h>

typedef __attribute__((ext_vector_type(8))) __bf16 bf16x8;
typedef __attribute__((ext_vector_type(4))) float f32x4;
typedef __attribute__((ext_vector_type(4))) float float4_t;
typedef __attribute__((ext_vector_type(4))) unsigned int uint4_t;

#define NB 4
#define TSEQ 4096
#define CD 1024
#define HD 64
#define NCH 8      // max KV chunks per q-tile
#define CHT 8      // KV tiles (of 64) per chunk

static __device__ __forceinline__ unsigned short f2bf(float f) {
    union { float f; unsigned u; } v; v.f = f;
    unsigned r = v.u + 0x7fffu + ((v.u >> 16) & 1u);
    return (unsigned short)(r >> 16);
}

// ---------------- W f32 -> bf16, permuted rows ----------------
// dest row blocks of 16: [q0,q32,q16,q48, k0,k32,k16,k48, v0,v16,v32,v48]
// so every RoPE (h,h+32) pair is an adjacent 16-row block pair.
__global__ __launch_bounds__(256) void wcvt_kernel(const float* __restrict__ wq,
                                                   const float* __restrict__ wk,
                                                   const float* __restrict__ wv,
                                                   unsigned short* __restrict__ wb) {
    int i = blockIdx.x * 256 + threadIdx.x;   // over 192*1024
    int j = i >> 10;                          // dest row
    int col = i & 1023;
    int jb = j >> 4, off = j & 15;
    int sub = ((jb & 1) << 5) | ((jb & 2) << 3);  // 0,32,16,48
    int srcrow = (jb < 8) ? (sub + off) : ((jb - 8) * 16 + off);
    const float* src = (jb < 4) ? wq : ((jb < 8) ? wk : wv);
    wb[i] = f2bf(src[srcrow * 1024 + col]);
}

// ---------------- fused QKV projection + RoPE (LDS-staged, 64x64 tiles) ----
// grid: (row_tile=256, col_tile=3); block = 4 waves; each wave 16 rows x 64 cols
__global__ __launch_bounds__(256) void qkv_kernel(const float* __restrict__ x,
                                                  const unsigned short* __restrict__ wb,
                                                  unsigned short* __restrict__ qo,
                                                  unsigned short* __restrict__ ko,
                                                  unsigned short* __restrict__ vt) {
    __shared__ unsigned short xs[64][72];
    __shared__ unsigned short ws[64][72];
    const int tid = threadIdx.x;
    const int wave = tid >> 6, lane = tid & 63;
    const int lr = lane & 15;
    const int lk = (lane >> 4) << 3;
    const int rowg = (lane >> 4) << 2;
    const int row0 = blockIdx.x * 64;
    const int cb = blockIdx.y * 64;   // permuted W row block (0=q, 64=k, 128=v)

    f32x4 acc[4];
#pragma unroll
    for (int i = 0; i < 4; ++i) acc[i] = (f32x4){0.f, 0.f, 0.f, 0.f};

    const int sr = tid >> 2;          // staging row 0..63
    const int sc = (tid & 3) << 4;    // staging col (elements) 0,16,32,48

    for (int k0 = 0; k0 < CD; k0 += 64) {
        __syncthreads();
        {   // stage x tile 64x64 f32 -> bf16 (coalesced 64B/thread)
            const float4_t* s4 =
                reinterpret_cast<const float4_t*>(x + (size_t)(row0 + sr) * CD + k0 + sc);
            alignas(16) unsigned short tmp[16];
#pragma unroll
            for (int j = 0; j < 4; ++j) {
                float4_t f = s4[j];
#pragma unroll
                for (int e = 0; e < 4; ++e) tmp[j * 4 + e] = f2bf(f[e]);
            }
            *reinterpret_cast<uint4_t*>(&xs[sr][sc]) = *reinterpret_cast<const uint4_t*>(&tmp[0]);
            *reinterpret_cast<uint4_t*>(&xs[sr][sc + 8]) = *reinterpret_cast<const uint4_t*>(&tmp[8]);
        }
        {   // stage W tile 64x64 bf16 (coalesced 32B/thread)
            const uint4_t* wsrc =
                reinterpret_cast<const uint4_t*>(wb + (size_t)(cb + sr) * CD + k0 + sc);
            *reinterpret_cast<uint4_t*>(&ws[sr][sc]) = wsrc[0];
            *reinterpret_cast<uint4_t*>(&ws[sr][sc + 8]) = wsrc[1];
        }
        __syncthreads();
#pragma unroll
        for (int kk = 0; kk < 2; ++kk) {
            bf16x8 a = *reinterpret_cast<const bf16x8*>(&xs[wave * 16 + lr][kk * 32 + lk]);
#pragma unroll
            for (int c = 0; c < 4; ++c) {
                bf16x8 bfr = *reinterpret_cast<const bf16x8*>(&ws[c * 16 + lr][kk * 32 + lk]);
                acc[c] = __builtin_amdgcn_mfma_f32_16x16x32_bf16(a, bfr, acc[c], 0, 0, 0);
            }
        }
    }

    // epilogue: RoPE + store
    const int gr0 = row0 + wave * 16 + rowg;      // global row (b*TSEQ + t)
    const int bidx = gr0 >> 12;
    const int tb = gr0 & (TSEQ - 1);
    if (blockIdx.y < 2) {
        unsigned short* o = (blockIdx.y == 0) ? qo : ko;
        const float l2b = 0.4152410118609215f;    // log2(10000)/32
        const float invf0 = exp2f(-(float)lr * l2b);
        const float invf1 = exp2f(-(float)(lr + 16) * l2b);
#pragma unroll
        for (int r = 0; r < 4; ++r) {
            float t = (float)(tb + r);
            float s0, c0, s1, c1;
            sincosf(t * invf0, &s0, &c0);
            sincosf(t * invf1, &s1, &c1);
            size_t ro = (size_t)(gr0 + r) * HD;
            float lo, hi;
            lo = acc[0][r]; hi = acc[1][r];
            o[ro + 0 + lr]  = f2bf(lo * c0 - hi * s0);
            o[ro + 32 + lr] = f2bf(hi * c0 + lo * s0);
            lo = acc[2][r]; hi = acc[3][r];
            o[ro + 16 + lr] = f2bf(lo * c1 - hi * s1);
            o[ro + 48 + lr] = f2bf(hi * c1 + lo * s1);
        }
    } else {
#pragma unroll
        for (int r = 0; r < 4; ++r) {
            size_t vbase = (size_t)bidx * HD * TSEQ + (size_t)(tb + r);
            vt[vbase + (size_t)(0 + lr) * TSEQ]  = f2bf(acc[0][r]);
            vt[vbase + (size_t)(16 + lr) * TSEQ] = f2bf(acc[1][r]);
            vt[vbase + (size_t)(32 + lr) * TSEQ] = f2bf(acc[2][r]);
            vt[vbase + (size_t)(48 + lr) * TSEQ] = f2bf(acc[3][r]);
        }
    }
}

// ---------------- causal flash attention, KV-split partials ----------------
// grid: (chunk=8, qt=64, b=B); block = 4 waves x 16 q-rows; KVBLK=64
__global__ __launch_bounds__(256) void attn_partial(const unsigned short* __restrict__ q,
                                                    const unsigned short* __restrict__ k,
                                                    const unsigned short* __restrict__ vt,
                                                    float* __restrict__ po,
                                                    float* __restrict__ pm,
                                                    float* __restrict__ pl) {
    const int chunk = blockIdx.x, qt = blockIdx.y, b = blockIdx.z;
    const int kt0 = chunk * CHT;
    if (kt0 > qt) return;
    const int ktend = min(qt, kt0 + CHT - 1);

    __shared__ unsigned short ks[64][72];
    __shared__ unsigned short vs[64][72];
    __shared__ unsigned short ps[4][16][72];
    const int tid = threadIdx.x;
    const int wave = tid >> 6, lane = tid & 63;
    const int lr = lane & 15;
    const int lk = (lane >> 4) << 3;
    const int rowg = (lane >> 4) << 2;
    const int qrow0 = qt * 64 + wave * 16;  // within batch

    const unsigned short* qbase = q + ((size_t)(b * TSEQ + qrow0 + lr)) * HD;
    bf16x8 qf0 = *reinterpret_cast<const bf16x8*>(qbase + lk);
    bf16x8 qf1 = *reinterpret_cast<const bf16x8*>(qbase + 32 + lk);

    f32x4 oacc[4];
#pragma unroll
    for (int i = 0; i < 4; ++i) oacc[i] = (f32x4){0.f, 0.f, 0.f, 0.f};
    float m[4] = {-INFINITY, -INFINITY, -INFINITY, -INFINITY};
    float lsum[4] = {0.f, 0.f, 0.f, 0.f};
    const float scale = 0.03125f;  // 1024^-0.5

    for (int kt = kt0; kt <= ktend; ++kt) {
        const int s0 = kt * 64;
        __syncthreads();
#pragma unroll
        for (int i = 0; i < 2; ++i) {
            int c = tid + (i << 8);
            int r = c >> 3;
            int c8 = (c & 7) << 3;
            *reinterpret_cast<uint4_t*>(&ks[r][c8]) =
                *reinterpret_cast<const uint4_t*>(k + (size_t)(b * TSEQ + s0 + r) * HD + c8);
            *reinterpret_cast<uint4_t*>(&vs[r][c8]) =
                *reinterpret_cast<const uint4_t*>(vt + ((size_t)b * HD + r) * TSEQ + s0 + c8);
        }
        __syncthreads();

        float sv[4][4];
        const bool diag = (kt == qt);
#pragma unroll
        for (int sc = 0; sc < 4; ++sc) {
            bf16x8 b0 = *reinterpret_cast<const bf16x8*>(&ks[sc * 16 + lr][lk]);
            bf16x8 b1 = *reinterpret_cast<const bf16x8*>(&ks[sc * 16 + lr][32 + lk]);
            f32x4 z = (f32x4){0.f, 0.f, 0.f, 0.f};
            z = __builtin_amdgcn_mfma_f32_16x16x32_bf16(qf0, b0, z, 0, 0, 0);
            z = __builtin_amdgcn_mfma_f32_16x16x32_bf16(qf1, b1, z, 0, 0, 0);
#pragma unroll
            for (int r = 0; r < 4; ++r) {
                float v = z[r] * scale;
                if (diag && (s0 + sc * 16 + lr) > (qrow0 + rowg + r)) v = -INFINITY;
                sv[sc][r] = v;
            }
        }

#pragma unroll
        for (int r = 0; r < 4; ++r) {
            float mx = fmaxf(fmaxf(sv[0][r], sv[1][r]), fmaxf(sv[2][r], sv[3][r]));
#pragma unroll
            for (int off = 1; off < 16; off <<= 1) mx = fmaxf(mx, __shfl_xor(mx, off, 64));
            float mnew = fmaxf(m[r], mx);
            float corr = __expf(m[r] - mnew);
            m[r] = mnew;
            float psum = 0.f;
#pragma unroll
            for (int sc = 0; sc < 4; ++sc) {
                float p = __expf(sv[sc][r] - mnew);
                psum += p;
                ps[wave][rowg + r][sc * 16 + lr] = f2bf(p);
            }
#pragma unroll
            for (int off = 1; off < 16; off <<= 1) psum += __shfl_xor(psum, off, 64);
            lsum[r] = lsum[r] * corr + psum;
#pragma unroll
            for (int hc = 0; hc < 4; ++hc) oacc[hc][r] *= corr;
        }

        bf16x8 pf0 = *reinterpret_cast<const bf16x8*>(&ps[wave][lr][lk]);
        bf16x8 pf1 = *reinterpret_cast<const bf16x8*>(&ps[wave][lr][32 + lk]);
#pragma unroll
        for (int hc = 0; hc < 4; ++hc) {
            bf16x8 v0 = *reinterpret_cast<const bf16x8*>(&vs[hc * 16 + lr][lk]);
            bf16x8 v1 = *reinterpret_cast<const bf16x8*>(&vs[hc * 16 + lr][32 + lk]);
            oacc[hc] = __builtin_amdgcn_mfma_f32_16x16x32_bf16(pf0, v0, oacc[hc], 0, 0, 0);
            oacc[hc] = __builtin_amdgcn_mfma_f32_16x16x32_bf16(pf1, v1, oacc[hc], 0, 0, 0);
        }
    }

    // write unnormalized partial + (m, l)
    const int slot = (((b << 6) + qt) << 3) + chunk;
    float* pob = po + (size_t)slot * 4096;
#pragma unroll
    for (int hc = 0; hc < 4; ++hc) {
#pragma unroll
        for (int r = 0; r < 4; ++r) {
            pob[(wave * 16 + rowg + r) * 64 + hc * 16 + lr] = oacc[hc][r];
        }
    }
    if (lr == 0) {
#pragma unroll
        for (int r = 0; r < 4; ++r) {
            pm[slot * 64 + wave * 16 + rowg + r] = m[r];
            pl[slot * 64 + wave * 16 + rowg + r] = lsum[r];
        }
    }
}

// ---------------- combine partials ----------------
__global__ __launch_bounds__(256) void attn_combine(const float* __restrict__ po,
                                                    const float* __restrict__ pm,
                                                    const float* __restrict__ pl,
                                                    float* __restrict__ out) {
    const int bq = blockIdx.x;       // b*64 + qt
    const int qt = bq & 63;
    const int nch = (qt >> 3) + 1;
    const int row = threadIdx.x >> 2;
    const int cg = (threadIdx.x & 3) << 4;
    const int sbase = bq << 3;

    float M = -INFINITY;
    for (int c = 0; c < nch; ++c) M = fmaxf(M, pm[(sbase + c) * 64 + row]);
    float L = 0.f;
    float acc[16];
#pragma unroll
    for (int j = 0; j < 16; ++j) acc[j] = 0.f;
    for (int c = 0; c < nch; ++c) {
        int s = sbase + c;
        float w = __expf(pm[s * 64 + row] - M);
        L += w * pl[s * 64 + row];
        const float4_t* p =
            reinterpret_cast<const float4_t*>(po + (size_t)s * 4096 + row * 64 + cg);
#pragma unroll
        for (int v4 = 0; v4 < 4; ++v4) {
            float4_t f = p[v4];
#pragma unroll
            for (int e = 0; e < 4; ++e) acc[v4 * 4 + e] += w * f[e];
        }
    }
    float inv = 1.f / L;
    size_t o = (size_t)bq * 4096 + row * 64 + cg;
#pragma unroll
    for (int j = 0; j < 16; ++j) out[o + j] = acc[j] * inv;
}

extern "C" void kernel_launch(void* const* d_in, const int* in_sizes, int n_in,
                              void* d_out, int out_size, void* d_ws, size_t ws_size,
                              hipStream_t stream) {
    const float* x = (const float*)d_in[0];
    const float* wq = (const float*)d_in[1];
    const float* wk = (const float*)d_in[2];
    const float* wv = (const float*)d_in[3];
    float* out = (float*)d_out;

    unsigned short* wb = (unsigned short*)d_ws;            // 196608 elems
    unsigned short* qb = wb + 3 * HD * CD;
    unsigned short* kb = qb + (size_t)NB * TSEQ * HD;
    unsigned short* vtb = kb + (size_t)NB * TSEQ * HD;
    float* po = (float*)(vtb + (size_t)NB * TSEQ * HD);    // 2048 slots * 4096 f32
    float* pm = po + (size_t)2048 * 4096;
    float* pl = pm + (size_t)2048 * 64;

    wcvt_kernel<<<768, 256, 0, stream>>>(wq, wk, wv, wb);
    qkv_kernel<<<dim3(256, 3), 256, 0, stream>>>(x, wb, qb, kb, vtb);
    attn_partial<<<dim3(NCH, 64, NB), 256, 0, stream>>>(qb, kb, vtb, po, pm, pl);
    attn_combine<<<NB * 64, 256, 0, stream>>>(po, pm, pl, out);
}

// Round 4
// 84.742 us; speedup vs baseline: 1.9339x; 1.1452x over previous
//
#include <hip/hip_runtime.h>
#include <hip/hip_bf16.h>
#include <math.h>

typedef __attribute__((ext_vector_type(8))) __bf16 bf16x8;
typedef __attribute__((ext_vector_type(4))) __bf16 bf16x4;
typedef __attribute__((ext_vector_type(4))) float f32x4;
typedef __attribute__((ext_vector_type(4))) float float4_t;
typedef __attribute__((ext_vector_type(4))) unsigned int uint4_t;

#define NB 4
#define TSEQ 4096
#define CD 1024
#define HD 64
#define NCH 8      // max KV chunks per q-tile
#define CHT 8      // KV tiles (of 64) per chunk

static __device__ __forceinline__ unsigned short f2bf(float f) {
    union { float f; unsigned u; } v; v.f = f;
    unsigned r = v.u + 0x7fffu + ((v.u >> 16) & 1u);
    return (unsigned short)(r >> 16);
}

// ---------------- W f32 -> bf16, permuted rows ----------------
// dest row blocks of 16: [q0,q32,q16,q48, k0,k32,k16,k48, v0,v16,v32,v48]
__global__ __launch_bounds__(256) void wcvt_kernel(const float* __restrict__ wq,
                                                   const float* __restrict__ wk,
                                                   const float* __restrict__ wv,
                                                   unsigned short* __restrict__ wb) {
    int i = blockIdx.x * 256 + threadIdx.x;   // over 192*1024
    int j = i >> 10;                          // dest row
    int col = i & 1023;
    int jb = j >> 4, off = j & 15;
    int sub = ((jb & 1) << 5) | ((jb & 2) << 3);  // 0,32,16,48
    int srcrow = (jb < 8) ? (sub + off) : ((jb - 8) * 16 + off);
    const float* src = (jb < 4) ? wq : ((jb < 8) ? wk : wv);
    wb[i] = f2bf(src[srcrow * 1024 + col]);
}

// ---------------- fused QKV projection + RoPE (LDS-staged, 64x64 tiles) ----
__global__ __launch_bounds__(256) void qkv_kernel(const float* __restrict__ x,
                                                  const unsigned short* __restrict__ wb,
                                                  unsigned short* __restrict__ qo,
                                                  unsigned short* __restrict__ ko,
                                                  unsigned short* __restrict__ vt) {
    __shared__ unsigned short xs[64][72];
    __shared__ unsigned short ws[64][72];
    const int tid = threadIdx.x;
    const int wave = tid >> 6, lane = tid & 63;
    const int lr = lane & 15;
    const int lk = (lane >> 4) << 3;
    const int rowg = (lane >> 4) << 2;
    const int row0 = blockIdx.x * 64;
    const int cb = blockIdx.y * 64;   // permuted W row block (0=q, 64=k, 128=v)

    f32x4 acc[4];
#pragma unroll
    for (int i = 0; i < 4; ++i) acc[i] = (f32x4){0.f, 0.f, 0.f, 0.f};

    const int sr = tid >> 2;          // staging row 0..63
    const int sc = (tid & 3) << 4;    // staging col (elements)

    for (int k0 = 0; k0 < CD; k0 += 64) {
        __syncthreads();
        {   // stage x tile 64x64 f32 -> bf16 (coalesced 64B/thread)
            const float4_t* s4 =
                reinterpret_cast<const float4_t*>(x + (size_t)(row0 + sr) * CD + k0 + sc);
            alignas(16) unsigned short tmp[16];
#pragma unroll
            for (int j = 0; j < 4; ++j) {
                float4_t f = s4[j];
#pragma unroll
                for (int e = 0; e < 4; ++e) tmp[j * 4 + e] = f2bf(f[e]);
            }
            *reinterpret_cast<uint4_t*>(&xs[sr][sc]) = *reinterpret_cast<const uint4_t*>(&tmp[0]);
            *reinterpret_cast<uint4_t*>(&xs[sr][sc + 8]) = *reinterpret_cast<const uint4_t*>(&tmp[8]);
        }
        {   // stage W tile 64x64 bf16 (coalesced 32B/thread)
            const uint4_t* wsrc =
                reinterpret_cast<const uint4_t*>(wb + (size_t)(cb + sr) * CD + k0 + sc);
            *reinterpret_cast<uint4_t*>(&ws[sr][sc]) = wsrc[0];
            *reinterpret_cast<uint4_t*>(&ws[sr][sc + 8]) = wsrc[1];
        }
        __syncthreads();
#pragma unroll
        for (int kk = 0; kk < 2; ++kk) {
            bf16x8 a = *reinterpret_cast<const bf16x8*>(&xs[wave * 16 + lr][kk * 32 + lk]);
#pragma unroll
            for (int c = 0; c < 4; ++c) {
                bf16x8 bfr = *reinterpret_cast<const bf16x8*>(&ws[c * 16 + lr][kk * 32 + lk]);
                acc[c] = __builtin_amdgcn_mfma_f32_16x16x32_bf16(a, bfr, acc[c], 0, 0, 0);
            }
        }
    }

    const int gr0 = row0 + wave * 16 + rowg;      // global row (b*TSEQ + t)
    const int bidx = gr0 >> 12;
    const int tb = gr0 & (TSEQ - 1);
    if (blockIdx.y < 2) {
        unsigned short* o = (blockIdx.y == 0) ? qo : ko;
        const float l2b = 0.4152410118609215f;    // log2(10000)/32
        const float invf0 = exp2f(-(float)lr * l2b);
        const float invf1 = exp2f(-(float)(lr + 16) * l2b);
#pragma unroll
        for (int r = 0; r < 4; ++r) {
            float t = (float)(tb + r);
            float s0, c0, s1, c1;
            sincosf(t * invf0, &s0, &c0);
            sincosf(t * invf1, &s1, &c1);
            size_t ro = (size_t)(gr0 + r) * HD;
            float lo, hi;
            lo = acc[0][r]; hi = acc[1][r];
            o[ro + 0 + lr]  = f2bf(lo * c0 - hi * s0);
            o[ro + 32 + lr] = f2bf(hi * c0 + lo * s0);
            lo = acc[2][r]; hi = acc[3][r];
            o[ro + 16 + lr] = f2bf(lo * c1 - hi * s1);
            o[ro + 48 + lr] = f2bf(hi * c1 + lo * s1);
        }
    } else {
#pragma unroll
        for (int r = 0; r < 4; ++r) {
            size_t vbase = (size_t)bidx * HD * TSEQ + (size_t)(tb + r);
            vt[vbase + (size_t)(0 + lr) * TSEQ]  = f2bf(acc[0][r]);
            vt[vbase + (size_t)(16 + lr) * TSEQ] = f2bf(acc[1][r]);
            vt[vbase + (size_t)(32 + lr) * TSEQ] = f2bf(acc[2][r]);
            vt[vbase + (size_t)(48 + lr) * TSEQ] = f2bf(acc[3][r]);
        }
    }
}

// ---------------- causal flash attention, KV-split partials ----------------
// Swapped QK^T (S^T = mfma(K,Q)): lane owns q-row lr, 16 k-vals in-register.
// grid: (chunk, qt=64, b=B); block = 4 waves x 16 q-rows; KVBLK=64
__global__ __launch_bounds__(256) void attn_partial(const unsigned short* __restrict__ q,
                                                    const unsigned short* __restrict__ k,
                                                    const unsigned short* __restrict__ vt,
                                                    float* __restrict__ po,
                                                    float* __restrict__ pm,
                                                    float* __restrict__ pl) {
    const int chunk = blockIdx.x, qt = blockIdx.y, b = blockIdx.z;
    const int kt0 = chunk * CHT;
    if (kt0 > qt) return;
    const int ktend = min(qt, kt0 + CHT - 1);

    __shared__ unsigned short ks[64][72];
    __shared__ unsigned short vs[64][72];
    __shared__ unsigned int ps[4][16][36];   // P as u32-pitched bf16 pairs
    const int tid = threadIdx.x;
    const int wave = tid >> 6, lane = tid & 63;
    const int lr = lane & 15;          // q-row owned by this lane (softmax view)
    const int g = lane >> 4;           // lane group
    const int lk = g << 3;
    const int qrow0 = qt * 64 + wave * 16;   // within batch

    const unsigned short* qbase = q + ((size_t)(b * TSEQ + qrow0 + lr)) * HD;
    bf16x8 qf0 = *reinterpret_cast<const bf16x8*>(qbase + lk);
    bf16x8 qf1 = *reinterpret_cast<const bf16x8*>(qbase + 32 + lk);

    f32x4 oacc[4];
#pragma unroll
    for (int i = 0; i < 4; ++i) oacc[i] = (f32x4){0.f, 0.f, 0.f, 0.f};
    float mreg = -INFINITY;   // log2-domain running max for q-row lr
    float lsum = 0.f;
    const float scale2 = 0.045084218764560315f;  // 1024^-0.5 * log2(e)

    // staging: 64B/thread, issue-early double-pump through registers
    const int srow = tid >> 3;
    const int scol = (tid & 7) << 3;
    const unsigned short* kbase = k + (size_t)b * TSEQ * HD;
    const unsigned short* vbase = vt + (size_t)b * HD * TSEQ;
    uint4_t kr0, kr1, vr0, vr1;
    {
        const int s0l = kt0 * 64;
        const unsigned short* kp = kbase + (size_t)(s0l + srow) * HD + scol;
        kr0 = *reinterpret_cast<const uint4_t*>(kp);
        kr1 = *reinterpret_cast<const uint4_t*>(kp + 32 * HD);
        const unsigned short* vp = vbase + (size_t)srow * TSEQ + s0l + scol;
        vr0 = *reinterpret_cast<const uint4_t*>(vp);
        vr1 = *reinterpret_cast<const uint4_t*>(vp + (size_t)32 * TSEQ);
    }

    for (int kt = kt0; kt <= ktend; ++kt) {
        const int s0 = kt * 64;
        __syncthreads();
        *reinterpret_cast<uint4_t*>(&ks[srow][scol]) = kr0;
        *reinterpret_cast<uint4_t*>(&ks[srow + 32][scol]) = kr1;
        *reinterpret_cast<uint4_t*>(&vs[srow][scol]) = vr0;
        *reinterpret_cast<uint4_t*>(&vs[srow + 32][scol]) = vr1;
        __syncthreads();
        if (kt < ktend) {   // prefetch next tile; latency hides under compute
            const int s0l = s0 + 64;
            const unsigned short* kp = kbase + (size_t)(s0l + srow) * HD + scol;
            kr0 = *reinterpret_cast<const uint4_t*>(kp);
            kr1 = *reinterpret_cast<const uint4_t*>(kp + 32 * HD);
            const unsigned short* vp = vbase + (size_t)srow * TSEQ + s0l + scol;
            vr0 = *reinterpret_cast<const uint4_t*>(vp);
            vr1 = *reinterpret_cast<const uint4_t*>(vp + (size_t)32 * TSEQ);
        }

        // S^T fragments: sv[scf][r] = S[q=lr][kpos = scf*16 + 4g + r]
        const bool diag = (kt == qt);
        float sv[4][4];
#pragma unroll
        for (int scf = 0; scf < 4; ++scf) {
            bf16x8 ka0 = *reinterpret_cast<const bf16x8*>(&ks[scf * 16 + lr][lk]);
            bf16x8 ka1 = *reinterpret_cast<const bf16x8*>(&ks[scf * 16 + lr][32 + lk]);
            f32x4 z = (f32x4){0.f, 0.f, 0.f, 0.f};
            z = __builtin_amdgcn_mfma_f32_16x16x32_bf16(ka0, qf0, z, 0, 0, 0);
            z = __builtin_amdgcn_mfma_f32_16x16x32_bf16(ka1, qf1, z, 0, 0, 0);
#pragma unroll
            for (int r = 0; r < 4; ++r) {
                float v = z[r] * scale2;
                if (diag && (s0 + scf * 16 + (g << 2) + r) > (qrow0 + lr)) v = -INFINITY;
                sv[scf][r] = v;
            }
        }

        // in-register online softmax for q-row lr (2+2 shfl total)
        float mx = -INFINITY;
#pragma unroll
        for (int scf = 0; scf < 4; ++scf)
#pragma unroll
            for (int r = 0; r < 4; ++r) mx = fmaxf(mx, sv[scf][r]);
        mx = fmaxf(mx, __shfl_xor(mx, 16, 64));
        mx = fmaxf(mx, __shfl_xor(mx, 32, 64));
        float mnew = fmaxf(mreg, mx);
        float corr = exp2f(mreg - mnew);
        mreg = mnew;
        float psum = 0.f;
#pragma unroll
        for (int scf = 0; scf < 4; ++scf) {
            bf16x4 pq;
#pragma unroll
            for (int r = 0; r < 4; ++r) {
                float p = exp2f(sv[scf][r] - mnew);
                psum += p;
                pq[r] = (__bf16)p;
            }
            *reinterpret_cast<bf16x4*>(&ps[wave][lr][scf * 8 + (g << 1)]) = pq;
        }
        psum += __shfl_xor(psum, 16, 64);
        psum += __shfl_xor(psum, 32, 64);
        lsum = lsum * corr + psum;

        // broadcast corr to O-layout rows (oacc row = 4g + r)
        float cr[4];
#pragma unroll
        for (int r = 0; r < 4; ++r) cr[r] = __shfl(corr, (g << 2) + r, 64);
#pragma unroll
        for (int hc = 0; hc < 4; ++hc)
#pragma unroll
            for (int r = 0; r < 4; ++r) oacc[hc][r] *= cr[r];

        // P V
        bf16x8 pf0 = *reinterpret_cast<const bf16x8*>(&ps[wave][lr][g << 2]);
        bf16x8 pf1 = *reinterpret_cast<const bf16x8*>(&ps[wave][lr][16 + (g << 2)]);
#pragma unroll
        for (int hc = 0; hc < 4; ++hc) {
            bf16x8 v0 = *reinterpret_cast<const bf16x8*>(&vs[hc * 16 + lr][lk]);
            bf16x8 v1 = *reinterpret_cast<const bf16x8*>(&vs[hc * 16 + lr][32 + lk]);
            oacc[hc] = __builtin_amdgcn_mfma_f32_16x16x32_bf16(pf0, v0, oacc[hc], 0, 0, 0);
            oacc[hc] = __builtin_amdgcn_mfma_f32_16x16x32_bf16(pf1, v1, oacc[hc], 0, 0, 0);
        }
    }

    // write unnormalized partial + (m2, l)
    const int slot = (((b << 6) + qt) << 3) + chunk;
    float* pob = po + (size_t)slot * 4096;
#pragma unroll
    for (int hc = 0; hc < 4; ++hc)
#pragma unroll
        for (int r = 0; r < 4; ++r)
            pob[(wave * 16 + (g << 2) + r) * 64 + hc * 16 + lr] = oacc[hc][r];
    if (g == 0) {
        pm[slot * 64 + wave * 16 + lr] = mreg;
        pl[slot * 64 + wave * 16 + lr] = lsum;
    }
}

// ---------------- combine partials (pm is log2-domain) ----------------
__global__ __launch_bounds__(256) void attn_combine(const float* __restrict__ po,
                                                    const float* __restrict__ pm,
                                                    const float* __restrict__ pl,
                                                    float* __restrict__ out) {
    const int bq = blockIdx.x;       // b*64 + qt
    const int qt = bq & 63;
    const int nch = (qt >> 3) + 1;
    const int row = threadIdx.x >> 2;
    const int cg = (threadIdx.x & 3) << 4;
    const int sbase = bq << 3;

    float M = -INFINITY;
    for (int c = 0; c < nch; ++c) M = fmaxf(M, pm[(sbase + c) * 64 + row]);
    float L = 0.f;
    float acc[16];
#pragma unroll
    for (int j = 0; j < 16; ++j) acc[j] = 0.f;
    for (int c = 0; c < nch; ++c) {
        int s = sbase + c;
        float w = exp2f(pm[s * 64 + row] - M);
        L += w * pl[s * 64 + row];
        const float4_t* p =
            reinterpret_cast<const float4_t*>(po + (size_t)s * 4096 + row * 64 + cg);
#pragma unroll
        for (int v4 = 0; v4 < 4; ++v4) {
            float4_t f = p[v4];
#pragma unroll
            for (int e = 0; e < 4; ++e) acc[v4 * 4 + e] += w * f[e];
        }
    }
    float inv = 1.f / L;
    size_t o = (size_t)bq * 4096 + row * 64 + cg;
#pragma unroll
    for (int j = 0; j < 16; ++j) out[o + j] = acc[j] * inv;
}

extern "C" void kernel_launch(void* const* d_in, const int* in_sizes, int n_in,
                              void* d_out, int out_size, void* d_ws, size_t ws_size,
                              hipStream_t stream) {
    const float* x = (const float*)d_in[0];
    const float* wq = (const float*)d_in[1];
    const float* wk = (const float*)d_in[2];
    const float* wv = (const float*)d_in[3];
    float* out = (float*)d_out;

    unsigned short* wb = (unsigned short*)d_ws;
    unsigned short* qb = wb + 3 * HD * CD;
    unsigned short* kb = qb + (size_t)NB * TSEQ * HD;
    unsigned short* vtb = kb + (size_t)NB * TSEQ * HD;
    float* po = (float*)(vtb + (size_t)NB * TSEQ * HD);
    float* pm = po + (size_t)2048 * 4096;
    float* pl = pm + (size_t)2048 * 64;

    wcvt_kernel<<<768, 256, 0, stream>>>(wq, wk, wv, wb);
    qkv_kernel<<<dim3(256, 3), 256, 0, stream>>>(x, wb, qb, kb, vtb);
    attn_partial<<<dim3(NCH, 64, NB), 256, 0, stream>>>(qb, kb, vtb, po, pm, pl);
    attn_combine<<<NB * 64, 256, 0, stream>>>(po, pm, pl, out);
}

// Round 5
// 73.530 us; speedup vs baseline: 2.2288x; 1.1525x over previous
//
#include <hip/hip_runtime.h>
#include <hip/hip_bf16.h>
#include <math.h>

typedef __attribute__((ext_vector_type(8))) __bf16 bf16x8;
typedef __attribute__((ext_vector_type(4))) float f32x4;
typedef __attribute__((ext_vector_type(16))) float f32x16;
typedef __attribute__((ext_vector_type(4))) float float4_t;
typedef __attribute__((ext_vector_type(4))) unsigned int uint4_t;

#define NB 4
#define TSEQ 4096
#define CD 1024
#define HD 64
#define NCH 8      // max KV chunks per q-tile
#define CHT 8      // KV tiles (of 64) per chunk

static __device__ __forceinline__ unsigned short f2bf(float f) {
    union { float f; unsigned u; } v; v.f = f;
    unsigned r = v.u + 0x7fffu + ((v.u >> 16) & 1u);
    return (unsigned short)(r >> 16);
}
static __device__ __forceinline__ unsigned int pack2bf(float lo, float hi) {
    return (unsigned int)f2bf(lo) | ((unsigned int)f2bf(hi) << 16);
}

// ---------------- W f32 -> bf16, permuted rows ----------------
// dest row blocks of 16: [q0,q32,q16,q48, k0,k32,k16,k48, v0,v16,v32,v48]
__global__ __launch_bounds__(256) void wcvt_kernel(const float* __restrict__ wq,
                                                   const float* __restrict__ wk,
                                                   const float* __restrict__ wv,
                                                   unsigned short* __restrict__ wb) {
    int i = blockIdx.x * 256 + threadIdx.x;   // over 192*1024
    int j = i >> 10;                          // dest row
    int col = i & 1023;
    int jb = j >> 4, off = j & 15;
    int sub = ((jb & 1) << 5) | ((jb & 2) << 3);  // 0,32,16,48
    int srcrow = (jb < 8) ? (sub + off) : ((jb - 8) * 16 + off);
    const float* src = (jb < 4) ? wq : ((jb < 8) ? wk : wv);
    wb[i] = f2bf(src[srcrow * 1024 + col]);
}

// ---------------- fused QKV projection + RoPE (LDS-staged, 64x64 tiles) ----
__global__ __launch_bounds__(256) void qkv_kernel(const float* __restrict__ x,
                                                  const unsigned short* __restrict__ wb,
                                                  unsigned short* __restrict__ qo,
                                                  unsigned short* __restrict__ ko,
                                                  unsigned short* __restrict__ vt) {
    __shared__ unsigned short xs[64][72];
    __shared__ unsigned short ws[64][72];
    const int tid = threadIdx.x;
    const int wave = tid >> 6, lane = tid & 63;
    const int lr = lane & 15;
    const int lk = (lane >> 4) << 3;
    const int rowg = (lane >> 4) << 2;
    const int row0 = blockIdx.x * 64;
    const int cb = blockIdx.y * 64;   // permuted W row block (0=q, 64=k, 128=v)

    f32x4 acc[4];
#pragma unroll
    for (int i = 0; i < 4; ++i) acc[i] = (f32x4){0.f, 0.f, 0.f, 0.f};

    const int sr = tid >> 2;          // staging row 0..63
    const int sc = (tid & 3) << 4;    // staging col (elements)

    for (int k0 = 0; k0 < CD; k0 += 64) {
        __syncthreads();
        {   // stage x tile 64x64 f32 -> bf16 (coalesced 64B/thread)
            const float4_t* s4 =
                reinterpret_cast<const float4_t*>(x + (size_t)(row0 + sr) * CD + k0 + sc);
            alignas(16) unsigned short tmp[16];
#pragma unroll
            for (int j = 0; j < 4; ++j) {
                float4_t f = s4[j];
#pragma unroll
                for (int e = 0; e < 4; ++e) tmp[j * 4 + e] = f2bf(f[e]);
            }
            *reinterpret_cast<uint4_t*>(&xs[sr][sc]) = *reinterpret_cast<const uint4_t*>(&tmp[0]);
            *reinterpret_cast<uint4_t*>(&xs[sr][sc + 8]) = *reinterpret_cast<const uint4_t*>(&tmp[8]);
        }
        {   // stage W tile 64x64 bf16 (coalesced 32B/thread)
            const uint4_t* wsrc =
                reinterpret_cast<const uint4_t*>(wb + (size_t)(cb + sr) * CD + k0 + sc);
            *reinterpret_cast<uint4_t*>(&ws[sr][sc]) = wsrc[0];
            *reinterpret_cast<uint4_t*>(&ws[sr][sc + 8]) = wsrc[1];
        }
        __syncthreads();
#pragma unroll
        for (int kk = 0; kk < 2; ++kk) {
            bf16x8 a = *reinterpret_cast<const bf16x8*>(&xs[wave * 16 + lr][kk * 32 + lk]);
#pragma unroll
            for (int c = 0; c < 4; ++c) {
                bf16x8 bfr = *reinterpret_cast<const bf16x8*>(&ws[c * 16 + lr][kk * 32 + lk]);
                acc[c] = __builtin_amdgcn_mfma_f32_16x16x32_bf16(a, bfr, acc[c], 0, 0, 0);
            }
        }
    }

    const int gr0 = row0 + wave * 16 + rowg;      // global row (b*TSEQ + t)
    const int bidx = gr0 >> 12;
    const int tb = gr0 & (TSEQ - 1);
    if (blockIdx.y < 2) {
        unsigned short* o = (blockIdx.y == 0) ? qo : ko;
        // fold attention scale (1/32 * log2(e)) into q only
        const float sc2 = (blockIdx.y == 0) ? 0.045084218764560315f : 1.0f;
        const float l2b = 0.4152410118609215f;    // log2(10000)/32
        const float invf0 = exp2f(-(float)lr * l2b);
        const float invf1 = exp2f(-(float)(lr + 16) * l2b);
#pragma unroll
        for (int r = 0; r < 4; ++r) {
            float t = (float)(tb + r);
            float s0, c0, s1, c1;
            sincosf(t * invf0, &s0, &c0);
            sincosf(t * invf1, &s1, &c1);
            size_t ro = (size_t)(gr0 + r) * HD;
            float lo, hi;
            lo = acc[0][r]; hi = acc[1][r];
            o[ro + 0 + lr]  = f2bf((lo * c0 - hi * s0) * sc2);
            o[ro + 32 + lr] = f2bf((hi * c0 + lo * s0) * sc2);
            lo = acc[2][r]; hi = acc[3][r];
            o[ro + 16 + lr] = f2bf((lo * c1 - hi * s1) * sc2);
            o[ro + 48 + lr] = f2bf((hi * c1 + lo * s1) * sc2);
        }
    } else {
#pragma unroll
        for (int r = 0; r < 4; ++r) {
            size_t vbase = (size_t)bidx * HD * TSEQ + (size_t)(tb + r);
            vt[vbase + (size_t)(0 + lr) * TSEQ]  = f2bf(acc[0][r]);
            vt[vbase + (size_t)(16 + lr) * TSEQ] = f2bf(acc[1][r]);
            vt[vbase + (size_t)(32 + lr) * TSEQ] = f2bf(acc[2][r]);
            vt[vbase + (size_t)(48 + lr) * TSEQ] = f2bf(acc[3][r]);
        }
    }
}

// ---------------- causal flash attention, KV-split partials ----------------
// 32x32 MFMA, swapped S^T = mfma(K,Q); O^T = mfma(V^T,P^T) so corr is
// lane-local. Block = 2 waves x 32 q-rows (QBLK=64); KVBLK=64.
// po layout: [slot][d 64][q 64].
__global__ __launch_bounds__(128, 3) void attn_partial(const unsigned short* __restrict__ q,
                                                       const unsigned short* __restrict__ k,
                                                       const unsigned short* __restrict__ vt,
                                                       float* __restrict__ po,
                                                       float* __restrict__ pm,
                                                       float* __restrict__ pl) {
    const int chunk = blockIdx.x, qt = blockIdx.y, b = blockIdx.z;
    const int kt0 = chunk * CHT;
    if (kt0 > qt) return;
    const int ktend = min(qt, kt0 + CHT - 1);

    __shared__ unsigned short ks[64][72];
    __shared__ unsigned short vs[64][72];
    const int tid = threadIdx.x;
    const int wave = tid >> 6, lane = tid & 63;
    const int l31 = lane & 31;
    const int h = lane >> 5;           // lane half
    const int h8 = h << 3;
    const int qrow0 = qt * 64 + wave * 32;   // this wave's q base (within batch)
    const int qpos = qrow0 + l31;            // q row owned by this lane

    // Q fragments (scale pre-folded at qkv): qf[s] = Q[qpos][16s + h8 .. +7]
    const unsigned short* qb_ = q + ((size_t)(b * TSEQ + qpos)) * HD + h8;
    bf16x8 qf[4];
#pragma unroll
    for (int s = 0; s < 4; ++s)
        qf[s] = *reinterpret_cast<const bf16x8*>(qb_ + 16 * s);

    f32x16 oacc[2];   // O^T tiles: row d = 32*dt + crow(r,h), col q = l31
#pragma unroll
    for (int dt = 0; dt < 2; ++dt)
#pragma unroll
        for (int r = 0; r < 16; ++r) oacc[dt][r] = 0.f;
    float mreg = -INFINITY;   // log2-domain running max
    float lsum = 0.f;

    // staging: thread covers one 32-col half of one row of K and V (64B each)
    const int srow = tid >> 1;
    const int scol = (tid & 1) << 5;
    const unsigned short* kbase = k + (size_t)b * TSEQ * HD;
    const unsigned short* vbase = vt + (size_t)b * HD * TSEQ;
    uint4_t kr[4], vr[4];
    {
        const int s0l = kt0 * 64;
        const unsigned short* kp = kbase + (size_t)(s0l + srow) * HD + scol;
        const unsigned short* vp = vbase + (size_t)srow * TSEQ + s0l + scol;
#pragma unroll
        for (int j = 0; j < 4; ++j) {
            kr[j] = *reinterpret_cast<const uint4_t*>(kp + 8 * j);
            vr[j] = *reinterpret_cast<const uint4_t*>(vp + 8 * j);
        }
    }

    for (int kt = kt0; kt <= ktend; ++kt) {
        const int s0 = kt * 64;
        __syncthreads();
#pragma unroll
        for (int j = 0; j < 4; ++j) {
            *reinterpret_cast<uint4_t*>(&ks[srow][scol + 8 * j]) = kr[j];
            *reinterpret_cast<uint4_t*>(&vs[srow][scol + 8 * j]) = vr[j];
        }
        __syncthreads();
        if (kt < ktend) {   // prefetch next tile under compute
            const int s0l = s0 + 64;
            const unsigned short* kp = kbase + (size_t)(s0l + srow) * HD + scol;
            const unsigned short* vp = vbase + (size_t)srow * TSEQ + s0l + scol;
#pragma unroll
            for (int j = 0; j < 4; ++j) {
                kr[j] = *reinterpret_cast<const uint4_t*>(kp + 8 * j);
                vr[j] = *reinterpret_cast<const uint4_t*>(vp + 8 * j);
            }
        }

        // S^T = K Q^T : two 32x32 C-tiles (kv blocks 0-31, 32-63)
        f32x16 sacc[2];
#pragma unroll
        for (int blk = 0; blk < 2; ++blk)
#pragma unroll
            for (int r = 0; r < 16; ++r) sacc[blk][r] = 0.f;
#pragma unroll
        for (int s = 0; s < 4; ++s) {
            bf16x8 ka = *reinterpret_cast<const bf16x8*>(&ks[l31][16 * s + h8]);
            bf16x8 kb2 = *reinterpret_cast<const bf16x8*>(&ks[32 + l31][16 * s + h8]);
            sacc[0] = __builtin_amdgcn_mfma_f32_32x32x16_bf16(ka, qf[s], sacc[0], 0, 0, 0);
            sacc[1] = __builtin_amdgcn_mfma_f32_32x32x16_bf16(kb2, qf[s], sacc[1], 0, 0, 0);
        }

        if (kt == qt) {   // causal mask on diagonal tile
#pragma unroll
            for (int blk = 0; blk < 2; ++blk)
#pragma unroll
                for (int r = 0; r < 16; ++r) {
                    int kvpos = s0 + 32 * blk + (r & 3) + ((r >> 2) << 3) + (h << 2);
                    if (kvpos > qpos) sacc[blk][r] = -INFINITY;
                }
        }

        // online softmax for q-row l31 (1+1 shfl)
        float mx = -INFINITY;
#pragma unroll
        for (int blk = 0; blk < 2; ++blk)
#pragma unroll
            for (int r = 0; r < 16; ++r) mx = fmaxf(mx, sacc[blk][r]);
        mx = fmaxf(mx, __shfl_xor(mx, 32, 64));
        float mnew = fmaxf(mreg, mx);
        float corr = __builtin_amdgcn_exp2f(mreg - mnew);
        mreg = mnew;
        float psum = 0.f;
        float pvv[2][16];
#pragma unroll
        for (int blk = 0; blk < 2; ++blk)
#pragma unroll
            for (int r = 0; r < 16; ++r) {
                float p = __builtin_amdgcn_exp2f(sacc[blk][r] - mnew);
                pvv[blk][r] = p;
                psum += p;
            }
        psum += __shfl_xor(psum, 32, 64);
        lsum = lsum * corr + psum;
#pragma unroll
        for (int dt = 0; dt < 2; ++dt)
#pragma unroll
            for (int r = 0; r < 16; ++r) oacc[dt][r] *= corr;

        // pack P rows to bf16 pair-words: cw[blk][G][w] = rows (8G+2w, 8G+2w+1)
        unsigned int cw[2][4][2];
#pragma unroll
        for (int blk = 0; blk < 2; ++blk)
#pragma unroll
            for (int G = 0; G < 4; ++G) {
                cw[blk][G][0] = pack2bf(pvv[blk][4 * G], pvv[blk][4 * G + 1]);
                cw[blk][G][1] = pack2bf(pvv[blk][4 * G + 2], pvv[blk][4 * G + 3]);
            }

        // P^T B-frags per k-slot (2 shfl_xor(32) each) + PV MFMAs
        const bool hif = (h == 1);
#pragma unroll
        for (int s = 0; s < 4; ++s) {
            const int blk = s >> 1, base = (s & 1) << 1;
            unsigned int a0 = cw[blk][base][0],     a1 = cw[blk][base][1];
            unsigned int b0 = cw[blk][base + 1][0], b1 = cw[blk][base + 1][1];
            unsigned int s0w = hif ? a0 : b0;
            unsigned int s1w = hif ? a1 : b1;
            unsigned int r0 = __shfl_xor(s0w, 32, 64);
            unsigned int r1 = __shfl_xor(s1w, 32, 64);
            uint4_t pw;
            pw[0] = hif ? r0 : a0;
            pw[1] = hif ? r1 : a1;
            pw[2] = hif ? b0 : r0;
            pw[3] = hif ? b1 : r1;
            bf16x8 pfrag = *reinterpret_cast<const bf16x8*>(&pw);
            bf16x8 v0 = *reinterpret_cast<const bf16x8*>(&vs[l31][16 * s + h8]);
            bf16x8 v1 = *reinterpret_cast<const bf16x8*>(&vs[32 + l31][16 * s + h8]);
            oacc[0] = __builtin_amdgcn_mfma_f32_32x32x16_bf16(v0, pfrag, oacc[0], 0, 0, 0);
            oacc[1] = __builtin_amdgcn_mfma_f32_32x32x16_bf16(v1, pfrag, oacc[1], 0, 0, 0);
        }
    }

    // write transposed partial [d][q] + (m2, l)
    const int slot = (((b << 6) + qt) << 3) + chunk;
    float* pob = po + (size_t)slot * 4096;
#pragma unroll
    for (int dt = 0; dt < 2; ++dt)
#pragma unroll
        for (int r = 0; r < 16; ++r) {
            int d = 32 * dt + (r & 3) + ((r >> 2) << 3) + (h << 2);
            pob[d * 64 + wave * 32 + l31] = oacc[dt][r];
        }
    if (h == 0) {
        pm[slot * 64 + wave * 32 + l31] = mreg;
        pl[slot * 64 + wave * 32 + l31] = lsum;
    }
}

// ---------------- combine partials (po is [slot][d][q], pm log2-domain) ----
__global__ __launch_bounds__(256) void attn_combine(const float* __restrict__ po,
                                                    const float* __restrict__ pm,
                                                    const float* __restrict__ pl,
                                                    float* __restrict__ out) {
    __shared__ float sm[64][68];
    const int bq = blockIdx.x;       // b*64 + qt
    const int qt = bq & 63;
    const int nch = (qt >> 3) + 1;
    const int qi = threadIdx.x & 63;
    const int dg = threadIdx.x >> 6;     // d group: d = dg*16 + j
    const int sbase = bq << 3;

    float M = -INFINITY;
    for (int c = 0; c < nch; ++c) M = fmaxf(M, pm[(sbase + c) * 64 + qi]);
    float L = 0.f;
    float acc[16];
#pragma unroll
    for (int j = 0; j < 16; ++j) acc[j] = 0.f;
    for (int c = 0; c < nch; ++c) {
        int s = sbase + c;
        float w = exp2f(pm[s * 64 + qi] - M);
        L += w * pl[s * 64 + qi];
        const float* p = po + (size_t)s * 4096 + qi;
#pragma unroll
        for (int j = 0; j < 16; ++j) acc[j] += w * p[(dg * 16 + j) * 64];
    }
    float inv = 1.f / L;
#pragma unroll
    for (int j = 0; j < 16; ++j) sm[qi][dg * 16 + j] = acc[j] * inv;
    __syncthreads();
    // coalesced out write: thread t -> row t>>2, 16-col chunk (t&3)
    const int row = threadIdx.x >> 2;
    const int cg = (threadIdx.x & 3) << 4;
    float4_t* dst = reinterpret_cast<float4_t*>(out + (size_t)bq * 4096 + row * 64 + cg);
#pragma unroll
    for (int v4 = 0; v4 < 4; ++v4) {
        float4_t f;
#pragma unroll
        for (int e = 0; e < 4; ++e) f[e] = sm[row][cg + v4 * 4 + e];
        dst[v4] = f;
    }
}

extern "C" void kernel_launch(void* const* d_in, const int* in_sizes, int n_in,
                              void* d_out, int out_size, void* d_ws, size_t ws_size,
                              hipStream_t stream) {
    const float* x = (const float*)d_in[0];
    const float* wq = (const float*)d_in[1];
    const float* wk = (const float*)d_in[2];
    const float* wv = (const float*)d_in[3];
    float* out = (float*)d_out;

    unsigned short* wb = (unsigned short*)d_ws;
    unsigned short* qb = wb + 3 * HD * CD;
    unsigned short* kb = qb + (size_t)NB * TSEQ * HD;
    unsigned short* vtb = kb + (size_t)NB * TSEQ * HD;
    float* po = (float*)(vtb + (size_t)NB * TSEQ * HD);
    float* pm = po + (size_t)2048 * 4096;
    float* pl = pm + (size_t)2048 * 64;

    wcvt_kernel<<<768, 256, 0, stream>>>(wq, wk, wv, wb);
    qkv_kernel<<<dim3(256, 3), 256, 0, stream>>>(x, wb, qb, kb, vtb);
    attn_partial<<<dim3(NCH, 64, NB), 128, 0, stream>>>(qb, kb, vtb, po, pm, pl);
    attn_combine<<<NB * 64, 256, 0, stream>>>(po, pm, pl, out);
}